// Round 4
// baseline (506.788 us; speedup 1.0000x reference)
//
#include <hip/hip_runtime.h>
#include <stdint.h>
#include <math.h>

// ---------------- workspace layout (bytes) ----------------
#define OFF_S1     0         // float2[32]                      (256 B)
#define OFF_W1T    256       // float[27*32] transposed conv1 w (3456 B)
#define OFF_T2     3712      // int[64]
#define OFF_P2     3968      // int[64]
#define OFF_T3     4224      // int[128]
#define OFF_P3     4736      // int[128]
#define OFF_T4     5248      // int[256]
#define OFF_P4     6272      // int[256]
#define OFF_W2     7296      // uint32[64*9]
#define OFF_W3     9600      // uint64[128*9]
#define OFF_W4     18816     // uint64[256*9*2]
#define OFF_A1     55680     // uint32[32*224*224]   6,422,528 B
#define OFF_A2     6478208   // uint64[32*112*112]   3,211,264 B
#define OFF_A3     9689472   // uint64[32*56*56*2]   1,605,632 B
#define OFF_A4     11295104  // uint32[32*28*28*8]     802,816 B
// total ~12.1 MB

// BN(x) >= 0 decided exactly as np fp32 would: fl(fl(x*sc)+sh) >= 0
static __device__ __forceinline__ float2 bnf(float g, float b, float m, float v) {
    float sc = __fdiv_rn(g, __fsqrt_rn(__fadd_rn(v, 1e-5f)));
    float sh = __fsub_rn(b, __fmul_rn(m, sc));
    return make_float2(sc, sh);
}
static __device__ __forceinline__ bool bnpos(float s, float2 p) {
    return __fadd_rn(__fmul_rn(s, p.x), p.y) >= 0.0f;
}

// minimal EVEN integer s in [-K, K+2] with bnpos((float)s) true (monotone: sc>0).
// T = K+2 means "never true". Conv sums are always even (per-tap contribution even).
static __device__ __forceinline__ int find_T(int K, float2 p) {
    int lo = -K - 2, hi = K + 2;
    while (lo + 2 < hi) {
        int mid = ((lo + hi) >> 1) & ~1;
        if (bnpos((float)mid, p)) hi = mid; else lo = mid;
    }
    return hi;
}

// ---------------- prep: ballot-parallel weight packing + thresholds ----------------
// wave tasks: wid 0..575 -> W2 word; 576..1727 -> W3; 1728..6335 -> W4.
// thread tasks (t = gtid - 405504): 0..863 W1T; 864..895 S1; 896..959 T2/P2;
//                                   960..1087 T3/P3; 1088..1343 T4/P4.
__global__ __launch_bounds__(256) void k_prep(
    const float* __restrict__ w1, const float* __restrict__ w2,
    const float* __restrict__ w3, const float* __restrict__ w4,
    const float* g1, const float* b1, const float* m1, const float* v1,
    const float* g2, const float* b2, const float* m2, const float* v2,
    const float* g3, const float* b3, const float* m3, const float* v3,
    const float* g4, const float* b4, const float* m4, const float* v4,
    float2* __restrict__ S1, float* __restrict__ W1T,
    int* __restrict__ T2, int* __restrict__ P2,
    int* __restrict__ T3, int* __restrict__ P3,
    int* __restrict__ T4, int* __restrict__ P4,
    uint32_t* __restrict__ W2, uint64_t* __restrict__ W3, uint64_t* __restrict__ W4)
{
    int gtid = blockIdx.x * 256 + threadIdx.x;
    int wid  = gtid >> 6;
    int lane = gtid & 63;

    if (wid < 576) {
        // W2: conv2_w [64][32][3][3]; bit ic = (w >= 0); lane = ic (<32)
        int oc = wid / 9, t = wid - oc * 9;
        float v = (lane < 32) ? w2[oc * 288 + lane * 9 + t] : -1.0f;
        uint64_t m = __ballot(v >= 0.0f);
        if (lane == 0) W2[wid] = (uint32_t)m;
    } else if (wid < 1728) {
        int i = wid - 576;
        int oc = i / 9, t = i - oc * 9;
        float v = w3[oc * 576 + lane * 9 + t];
        uint64_t m = __ballot(v >= 0.0f);
        if (lane == 0) W3[i] = m;
    } else if (wid < 6336) {
        int i = wid - 1728;
        int oc = i / 18, rem = i - oc * 18;
        int t = rem >> 1, h = rem & 1;
        float v = w4[oc * 1152 + (h * 64 + lane) * 9 + t];
        uint64_t m = __ballot(v >= 0.0f);
        if (lane == 0) W4[i] = m;
    } else {
        int t = gtid - 405504;
        if (t < 864) {
            int k = t >> 5, oc = t & 31;
            W1T[t] = w1[oc * 27 + k];          // W1T[k][oc]
        } else if (t < 896) {
            int c = t - 864;
            S1[c] = bnf(g1[c], b1[c], m1[c], v1[c]);
        } else if (t < 960) {
            int c = t - 896;
            int T = find_T(288, bnf(g2[c], b2[c], m2[c], v2[c]));
            T2[c] = T; P2[c] = (288 - T) >> 1;
        } else if (t < 1088) {
            int c = t - 960;
            int T = find_T(576, bnf(g3[c], b3[c], m3[c], v3[c]));
            T3[c] = T; P3[c] = (576 - T) >> 1;
        } else if (t < 1344) {
            int c = t - 1088;
            int T = find_T(1152, bnf(g4[c], b4[c], m4[c], v4[c]));
            T4[c] = T; P4[c] = (1152 - T) >> 1;
        }
    }
}

// ---------------- conv1 (real, fp32) + bn1 + binarize + pack ----------------
// x: [32][3][224][224] f32 ; out A1: [32][224][224] u32 (bit oc)
// Weights via uniform (scalar) loads from W1T[k][oc] float4 — no LDS.
__global__ __launch_bounds__(256) void k_conv1(
    const float* __restrict__ x, const float* __restrict__ W1T,
    const float2* __restrict__ S1, uint32_t* __restrict__ A1)
{
    int tid = threadIdx.x;
    int idx = blockIdx.x * 256 + tid;       // [b][y][xpair], xpair 0..111
    int xp = idx % 112;
    int t  = idx / 112;
    int y  = t % 224;
    int b  = t / 224;
    int xc = xp * 2;

    const float* xb = x + (size_t)b * 3 * 50176;
    float xin[3][3][4];
    #pragma unroll
    for (int ic = 0; ic < 3; ic++)
        #pragma unroll
        for (int ky = 0; ky < 3; ky++)
            #pragma unroll
            for (int cx = 0; cx < 4; cx++) {
                int iy = y - 1 + ky, ix = xc - 1 + cx;
                float v = 0.0f;
                if ((unsigned)iy < 224u && (unsigned)ix < 224u)
                    v = xb[ic * 50176 + iy * 224 + ix];
                xin[ic][ky][cx] = v;
            }

    float acc0[32], acc1[32];
    #pragma unroll
    for (int oc = 0; oc < 32; oc++) { acc0[oc] = 0.0f; acc1[oc] = 0.0f; }

    const float4* w4p = (const float4*)W1T;   // [k][8] float4, uniform
    #pragma unroll
    for (int k = 0; k < 27; k++) {
        int ic = k / 9, r = (k % 9) / 3, c = k % 3;
        float a0 = xin[ic][r][c];
        float a1 = xin[ic][r][c + 1];
        #pragma unroll
        for (int g8 = 0; g8 < 8; g8++) {
            float4 w = w4p[k * 8 + g8];
            acc0[g8 * 4 + 0] = fmaf(a0, w.x, acc0[g8 * 4 + 0]);
            acc0[g8 * 4 + 1] = fmaf(a0, w.y, acc0[g8 * 4 + 1]);
            acc0[g8 * 4 + 2] = fmaf(a0, w.z, acc0[g8 * 4 + 2]);
            acc0[g8 * 4 + 3] = fmaf(a0, w.w, acc0[g8 * 4 + 3]);
            acc1[g8 * 4 + 0] = fmaf(a1, w.x, acc1[g8 * 4 + 0]);
            acc1[g8 * 4 + 1] = fmaf(a1, w.y, acc1[g8 * 4 + 1]);
            acc1[g8 * 4 + 2] = fmaf(a1, w.z, acc1[g8 * 4 + 2]);
            acc1[g8 * 4 + 3] = fmaf(a1, w.w, acc1[g8 * 4 + 3]);
        }
    }

    uint32_t bits0 = 0, bits1 = 0;
    #pragma unroll
    for (int oc = 0; oc < 32; oc++) {
        float2 p = S1[oc];                    // uniform
        bits0 |= (uint32_t)bnpos(acc0[oc], p) << oc;
        bits1 |= (uint32_t)bnpos(acc1[oc], p) << oc;
    }
    uint2* dst = (uint2*)(A1 + (size_t)b * 50176 + y * 224 + xc);
    *dst = make_uint2(bits0, bits1);
}

// ---------------- conv2 (binary, stride 2): A1 u32 -> A2 [32][112][112] u64 ----------------
__global__ __launch_bounds__(256) void k_conv2(
    const uint32_t* __restrict__ A1, const uint32_t* __restrict__ W2,
    const int* __restrict__ T2, const int* __restrict__ P2,
    uint64_t* __restrict__ A2)
{
    int idx = blockIdx.x * 256 + threadIdx.x;   // 32*112*112
    int ox = idx % 112;
    int t  = idx / 112;
    int oy = t % 112;
    int b  = t / 112;

    const uint32_t* ab = A1 + (size_t)b * 50176;
    uint32_t xw[9];
    unsigned vm = 0;
    #pragma unroll
    for (int ky = 0; ky < 3; ky++)
        #pragma unroll
        for (int kx = 0; kx < 3; kx++) {
            int iy = 2 * oy - 1 + ky, ix = 2 * ox - 1 + kx;
            int ti = ky * 3 + kx;
            bool ok = ((unsigned)iy < 224u) && ((unsigned)ix < 224u);
            xw[ti] = ok ? ab[iy * 224 + ix] : 0u;
            vm |= (unsigned)ok << ti;
        }

    uint64_t bits = 0;
    if (vm == 0x1FFu) {
        for (int oc = 0; oc < 64; oc++) {
            const uint32_t* wp = W2 + oc * 9;   // uniform -> SGPRs
            int pc = 0;
            #pragma unroll
            for (int ti = 0; ti < 9; ti++) pc += __popc(xw[ti] ^ wp[ti]);
            bits |= (uint64_t)(pc <= P2[oc]) << oc;
        }
    } else {
        int nv = __popc(vm);
        for (int oc = 0; oc < 64; oc++) {
            const uint32_t* wp = W2 + oc * 9;
            int pc = 0;
            #pragma unroll
            for (int ti = 0; ti < 9; ti++)
                if ((vm >> ti) & 1u) pc += __popc(xw[ti] ^ wp[ti]);
            bits |= (uint64_t)(pc <= ((32 * nv - T2[oc]) >> 1)) << oc;
        }
    }
    A2[idx] = bits;
}

// ---------------- conv3 (binary, stride 2): A2 -> A3 [32][56][56][2] u64 ----------------
__global__ __launch_bounds__(256) void k_conv3(
    const uint64_t* __restrict__ A2, const uint64_t* __restrict__ W3,
    const int* __restrict__ T3, const int* __restrict__ P3,
    uint64_t* __restrict__ A3)
{
    int idx = blockIdx.x * 256 + threadIdx.x;   // 32*56*56*2
    int g  = idx & 1;
    int p  = idx >> 1;
    int ox = p % 56;
    int t  = p / 56;
    int oy = t % 56;
    int b  = t / 56;

    const uint64_t* ab = A2 + (size_t)b * 12544;
    uint64_t xw[9];
    unsigned vm = 0;
    #pragma unroll
    for (int ky = 0; ky < 3; ky++)
        #pragma unroll
        for (int kx = 0; kx < 3; kx++) {
            int iy = 2 * oy - 1 + ky, ix = 2 * ox - 1 + kx;
            int ti = ky * 3 + kx;
            bool ok = ((unsigned)iy < 112u) && ((unsigned)ix < 112u);
            xw[ti] = ok ? ab[iy * 112 + ix] : 0ull;
            vm |= (unsigned)ok << ti;
        }

    int ocbase = g * 64;
    uint64_t bits = 0;
    if (vm == 0x1FFu) {
        for (int o = 0; o < 64; o++) {
            int oc = ocbase + o;
            const uint64_t* wp = W3 + oc * 9;   // uniform -> SGPRs
            int pc = 0;
            #pragma unroll
            for (int ti = 0; ti < 9; ti++) pc += __popcll(xw[ti] ^ wp[ti]);
            bits |= (uint64_t)(pc <= P3[oc]) << o;
        }
    } else {
        int nv = __popc(vm);
        for (int o = 0; o < 64; o++) {
            int oc = ocbase + o;
            const uint64_t* wp = W3 + oc * 9;
            int pc = 0;
            #pragma unroll
            for (int ti = 0; ti < 9; ti++)
                if ((vm >> ti) & 1u) pc += __popcll(xw[ti] ^ wp[ti]);
            bits |= (uint64_t)(pc <= ((64 * nv - T3[oc]) >> 1)) << o;
        }
    }
    A3[idx] = bits;   // [b][y][x][g]
}

// ---------------- conv4 (binary, stride 2): A3 -> A4 [32][28][28][8] u32 ----------------
// 8 oc-groups of 32: 784 blocks (2x occupancy vs 64-oc split)
__global__ __launch_bounds__(256) void k_conv4(
    const uint64_t* __restrict__ A3, const uint64_t* __restrict__ W4,
    const int* __restrict__ T4, const int* __restrict__ P4,
    uint32_t* __restrict__ A4)
{
    int idx = blockIdx.x * 256 + threadIdx.x;   // 32*28*28*8
    int g  = idx & 7;
    int p  = idx >> 3;
    int ox = p % 28;
    int t  = p / 28;
    int oy = t % 28;
    int b  = t / 28;

    const uint64_t* ab = A3 + (size_t)b * 3136 * 2;
    uint64_t x0[9], x1[9];
    unsigned vm = 0;
    #pragma unroll
    for (int ky = 0; ky < 3; ky++)
        #pragma unroll
        for (int kx = 0; kx < 3; kx++) {
            int iy = 2 * oy - 1 + ky, ix = 2 * ox - 1 + kx;
            int ti = ky * 3 + kx;
            bool ok = ((unsigned)iy < 56u) && ((unsigned)ix < 56u);
            int base = (iy * 56 + ix) * 2;
            x0[ti] = ok ? ab[base + 0] : 0ull;
            x1[ti] = ok ? ab[base + 1] : 0ull;
            vm |= (unsigned)ok << ti;
        }

    int ocbase = g * 32;
    uint32_t bits = 0;
    if (vm == 0x1FFu) {
        for (int o = 0; o < 32; o++) {
            int oc = ocbase + o;
            const uint64_t* wp = W4 + oc * 18;  // uniform -> SGPRs
            int pc = 0;
            #pragma unroll
            for (int ti = 0; ti < 9; ti++) {
                pc += __popcll(x0[ti] ^ wp[ti * 2 + 0]);
                pc += __popcll(x1[ti] ^ wp[ti * 2 + 1]);
            }
            bits |= (uint32_t)(pc <= P4[oc]) << o;
        }
    } else {
        int nv = __popc(vm);
        for (int o = 0; o < 32; o++) {
            int oc = ocbase + o;
            const uint64_t* wp = W4 + oc * 18;
            int pc = 0;
            #pragma unroll
            for (int ti = 0; ti < 9; ti++)
                if ((vm >> ti) & 1u) {
                    pc += __popcll(x0[ti] ^ wp[ti * 2 + 0]);
                    pc += __popcll(x1[ti] ^ wp[ti * 2 + 1]);
                }
            bits |= (uint32_t)(pc <= ((128 * nv - T4[oc]) >> 1)) << o;
        }
    }
    A4[idx] = bits;   // [b][y][x][g8]
}

// ---------------- mean over HxW + fc ----------------
// 32 blocks x 1024 threads: tid = chunk(4) x channel(256)
__global__ __launch_bounds__(1024) void k_tail(
    const uint32_t* __restrict__ A4, const float* __restrict__ fcw,
    const float* __restrict__ fcb, float* __restrict__ out)
{
    int b = blockIdx.x;
    int tid = threadIdx.x;
    int c = tid & 255, chunk = tid >> 8;
    int g = c >> 5, bit = c & 31;
    const uint32_t* ab = A4 + (size_t)b * 784 * 8;
    int cnt = 0;
    for (int p = chunk * 196; p < (chunk + 1) * 196; p++)
        cnt += (int)((ab[p * 8 + g] >> bit) & 1u);

    __shared__ int cnts[4][256];
    __shared__ double r0[256], r1[256];
    cnts[chunk][c] = cnt;
    __syncthreads();
    if (tid < 256) {
        int tot = cnts[0][c] + cnts[1][c] + cnts[2][c] + cnts[3][c];
        double mean = (2.0 * (double)tot - 784.0) * (1.0 / 784.0);
        r0[c] = (double)fcw[c]       * mean;
        r1[c] = (double)fcw[256 + c] * mean;
    }
    __syncthreads();
    for (int s = 128; s > 0; s >>= 1) {
        if (tid < s) { r0[tid] += r0[tid + s]; r1[tid] += r1[tid + s]; }
        __syncthreads();
    }
    if (tid == 0) {
        out[b * 2 + 0] = (float)(r0[0] + (double)fcb[0]);
        out[b * 2 + 1] = (float)(r1[0] + (double)fcb[1]);
    }
}

extern "C" void kernel_launch(void* const* d_in, const int* in_sizes, int n_in,
                              void* d_out, int out_size, void* d_ws, size_t ws_size,
                              hipStream_t stream) {
    const float* x   = (const float*)d_in[0];
    const float* w1  = (const float*)d_in[1];
    const float* w2  = (const float*)d_in[2];
    const float* w3  = (const float*)d_in[3];
    const float* w4  = (const float*)d_in[4];
    const float* g1 = (const float*)d_in[5],  *b1 = (const float*)d_in[6],
               * m1 = (const float*)d_in[7],  *v1 = (const float*)d_in[8];
    const float* g2 = (const float*)d_in[9],  *b2 = (const float*)d_in[10],
               * m2 = (const float*)d_in[11], *v2 = (const float*)d_in[12];
    const float* g3 = (const float*)d_in[13], *b3 = (const float*)d_in[14],
               * m3 = (const float*)d_in[15], *v3 = (const float*)d_in[16];
    const float* g4 = (const float*)d_in[17], *b4 = (const float*)d_in[18],
               * m4 = (const float*)d_in[19], *v4 = (const float*)d_in[20];
    const float* fcw = (const float*)d_in[21];
    const float* fcb = (const float*)d_in[22];
    float* out = (float*)d_out;

    char* ws = (char*)d_ws;
    float2*   S1  = (float2*)(ws + OFF_S1);
    float*    W1T = (float*)(ws + OFF_W1T);
    int*      T2  = (int*)(ws + OFF_T2);
    int*      P2  = (int*)(ws + OFF_P2);
    int*      T3  = (int*)(ws + OFF_T3);
    int*      P3  = (int*)(ws + OFF_P3);
    int*      T4  = (int*)(ws + OFF_T4);
    int*      P4  = (int*)(ws + OFF_P4);
    uint32_t* W2  = (uint32_t*)(ws + OFF_W2);
    uint64_t* W3  = (uint64_t*)(ws + OFF_W3);
    uint64_t* W4  = (uint64_t*)(ws + OFF_W4);
    uint32_t* A1  = (uint32_t*)(ws + OFF_A1);
    uint64_t* A2  = (uint64_t*)(ws + OFF_A2);
    uint64_t* A3  = (uint64_t*)(ws + OFF_A3);
    uint32_t* A4  = (uint32_t*)(ws + OFF_A4);

    hipLaunchKernelGGL(k_prep, dim3(1590), dim3(256), 0, stream,
                       w1, w2, w3, w4,
                       g1, b1, m1, v1, g2, b2, m2, v2,
                       g3, b3, m3, v3, g4, b4, m4, v4,
                       S1, W1T, T2, P2, T3, P3, T4, P4, W2, W3, W4);
    hipLaunchKernelGGL(k_conv1, dim3(3136), dim3(256), 0, stream, x, W1T, S1, A1);
    hipLaunchKernelGGL(k_conv2, dim3(1568), dim3(256), 0, stream, A1, W2, T2, P2, A2);
    hipLaunchKernelGGL(k_conv3, dim3(784),  dim3(256), 0, stream, A2, W3, T3, P3, A3);
    hipLaunchKernelGGL(k_conv4, dim3(784),  dim3(256), 0, stream, A3, W4, T4, P4, A4);
    hipLaunchKernelGGL(k_tail,  dim3(32),   dim3(1024), 0, stream, A4, fcw, fcb, out);
}

// Round 5
// 239.207 us; speedup vs baseline: 2.1186x; 2.1186x over previous
//
#include <hip/hip_runtime.h>
#include <stdint.h>
#include <math.h>

// ---------------- workspace layout (bytes) ----------------
#define OFF_S1     0         // float2[32]
#define OFF_W1T    256       // float[27*32] (unused by conv1 now; kept)
#define OFF_T2     3712      // int[64]
#define OFF_P2     3968      // int[64]
#define OFF_T3     4224      // int[128]
#define OFF_P3     4736      // int[128]
#define OFF_T4     5248      // int[256]
#define OFF_P4     6272      // int[256]
#define OFF_W2     7296      // uint32[64*9]
#define OFF_W3     9600      // uint64[128*9]
#define OFF_W4     18816     // uint64[256*9*2]  (16B aligned)
#define OFF_A1     55680     // uint32[32*224*224]   6,422,528 B
#define OFF_A2     6478208   // uint64[32*112*112]   3,211,264 B
#define OFF_A3     9689472   // uint64[2][32*56*56]  1,605,632 B (planar)
#define OFF_A4     11295104  // uint64[4][32*28*28]    802,816 B (planar)

// BN(x) >= 0 decided exactly as np fp32 would: fl(fl(x*sc)+sh) >= 0
static __device__ __forceinline__ float2 bnf(float g, float b, float m, float v) {
    float sc = __fdiv_rn(g, __fsqrt_rn(__fadd_rn(v, 1e-5f)));
    float sh = __fsub_rn(b, __fmul_rn(m, sc));
    return make_float2(sc, sh);
}
static __device__ __forceinline__ bool bnpos(float s, float2 p) {
    return __fadd_rn(__fmul_rn(s, p.x), p.y) >= 0.0f;
}
// minimal EVEN integer s with bnpos((float)s) true (monotone, sc>0); K+2 = never
static __device__ __forceinline__ int find_T(int K, float2 p) {
    int lo = -K - 2, hi = K + 2;
    while (lo + 2 < hi) {
        int mid = ((lo + hi) >> 1) & ~1;
        if (bnpos((float)mid, p)) hi = mid; else lo = mid;
    }
    return hi;
}

// ---------------- prep (validated in R4): ballot packing + integer thresholds ----
__global__ __launch_bounds__(256) void k_prep(
    const float* __restrict__ w1, const float* __restrict__ w2,
    const float* __restrict__ w3, const float* __restrict__ w4,
    const float* g1, const float* b1, const float* m1, const float* v1,
    const float* g2, const float* b2, const float* m2, const float* v2,
    const float* g3, const float* b3, const float* m3, const float* v3,
    const float* g4, const float* b4, const float* m4, const float* v4,
    float2* __restrict__ S1, float* __restrict__ W1T,
    int* __restrict__ T2, int* __restrict__ P2,
    int* __restrict__ T3, int* __restrict__ P3,
    int* __restrict__ T4, int* __restrict__ P4,
    uint32_t* __restrict__ W2, uint64_t* __restrict__ W3, uint64_t* __restrict__ W4)
{
    int gtid = blockIdx.x * 256 + threadIdx.x;
    int wid  = gtid >> 6;
    int lane = gtid & 63;

    if (wid < 576) {
        int oc = wid / 9, t = wid - oc * 9;
        float v = (lane < 32) ? w2[oc * 288 + lane * 9 + t] : -1.0f;
        uint64_t m = __ballot(v >= 0.0f);
        if (lane == 0) W2[wid] = (uint32_t)m;
    } else if (wid < 1728) {
        int i = wid - 576;
        int oc = i / 9, t = i - oc * 9;
        float v = w3[oc * 576 + lane * 9 + t];
        uint64_t m = __ballot(v >= 0.0f);
        if (lane == 0) W3[i] = m;
    } else if (wid < 6336) {
        int i = wid - 1728;
        int oc = i / 18, rem = i - oc * 18;
        int t = rem >> 1, h = rem & 1;
        float v = w4[oc * 1152 + (h * 64 + lane) * 9 + t];
        uint64_t m = __ballot(v >= 0.0f);
        if (lane == 0) W4[i] = m;
    } else {
        int t = gtid - 405504;
        if (t < 864) {
            int k = t >> 5, oc = t & 31;
            W1T[t] = w1[oc * 27 + k];
        } else if (t < 896) {
            int c = t - 864;
            S1[c] = bnf(g1[c], b1[c], m1[c], v1[c]);
        } else if (t < 960) {
            int c = t - 896;
            int T = find_T(288, bnf(g2[c], b2[c], m2[c], v2[c]));
            T2[c] = T; P2[c] = (288 - T) >> 1;
        } else if (t < 1088) {
            int c = t - 960;
            int T = find_T(576, bnf(g3[c], b3[c], m3[c], v3[c]));
            T3[c] = T; P3[c] = (576 - T) >> 1;
        } else if (t < 1344) {
            int c = t - 1088;
            int T = find_T(1152, bnf(g4[c], b4[c], m4[c], v4[c]));
            T4[c] = T; P4[c] = (1152 - T) >> 1;
        }
    }
}

// ---------------- conv1 (R3-proven: LDS weights, broadcast b128 reads) ----------
__global__ __launch_bounds__(256) void k_conv1(
    const float* __restrict__ x, const float* __restrict__ w1,
    const float2* __restrict__ S1g, uint32_t* __restrict__ A1)
{
    __shared__ float  wl[27 * 32];   // [k][oc]
    __shared__ float2 s1[32];
    int tid = threadIdx.x;
    for (int i = tid; i < 864; i += 256) {
        int k = i >> 5, oc = i & 31;
        wl[i] = w1[oc * 27 + k];
    }
    if (tid < 32) s1[tid] = S1g[tid];
    __syncthreads();

    int idx = blockIdx.x * 256 + tid;       // [b][y][xpair]
    int xp = idx % 112;
    int t  = idx / 112;
    int y  = t % 224;
    int b  = t / 224;
    int xc = xp * 2;

    const float* xb = x + (size_t)b * 3 * 50176;
    float xin[3][3][4];
    #pragma unroll
    for (int ic = 0; ic < 3; ic++)
        #pragma unroll
        for (int ky = 0; ky < 3; ky++)
            #pragma unroll
            for (int cx = 0; cx < 4; cx++) {
                int iy = y - 1 + ky, ix = xc - 1 + cx;
                float v = 0.0f;
                if ((unsigned)iy < 224u && (unsigned)ix < 224u)
                    v = xb[ic * 50176 + iy * 224 + ix];
                xin[ic][ky][cx] = v;
            }

    float acc0[32], acc1[32];
    #pragma unroll
    for (int oc = 0; oc < 32; oc++) { acc0[oc] = 0.0f; acc1[oc] = 0.0f; }

    const float4* wl4 = (const float4*)wl;
    #pragma unroll
    for (int k = 0; k < 27; k++) {
        int ic = k / 9, r = (k % 9) / 3, c = k % 3;
        float a0 = xin[ic][r][c];
        float a1 = xin[ic][r][c + 1];
        #pragma unroll
        for (int g8 = 0; g8 < 8; g8++) {
            float4 w = wl4[k * 8 + g8];
            acc0[g8 * 4 + 0] = fmaf(a0, w.x, acc0[g8 * 4 + 0]);
            acc0[g8 * 4 + 1] = fmaf(a0, w.y, acc0[g8 * 4 + 1]);
            acc0[g8 * 4 + 2] = fmaf(a0, w.z, acc0[g8 * 4 + 2]);
            acc0[g8 * 4 + 3] = fmaf(a0, w.w, acc0[g8 * 4 + 3]);
            acc1[g8 * 4 + 0] = fmaf(a1, w.x, acc1[g8 * 4 + 0]);
            acc1[g8 * 4 + 1] = fmaf(a1, w.y, acc1[g8 * 4 + 1]);
            acc1[g8 * 4 + 2] = fmaf(a1, w.z, acc1[g8 * 4 + 2]);
            acc1[g8 * 4 + 3] = fmaf(a1, w.w, acc1[g8 * 4 + 3]);
        }
    }

    uint32_t bits0 = 0, bits1 = 0;
    #pragma unroll
    for (int oc = 0; oc < 32; oc++) {
        bits0 |= (uint32_t)bnpos(acc0[oc], s1[oc]) << oc;
        bits1 |= (uint32_t)bnpos(acc1[oc], s1[oc]) << oc;
    }
    uint2* dst = (uint2*)(A1 + (size_t)b * 50176 + y * 224 + xc);
    *dst = make_uint2(bits0, bits1);
}

// ======== ballot-structured binary convs: lane = oc, LDS = activations ========
#define C2_LW 114
#define C3_LW 57
#define C4_LW 29

template<unsigned VM>
static __device__ __forceinline__ bool px2(const uint32_t* row, int c0,
                                           const uint32_t* wreg, int T) {
    int pc = 0;
    #pragma unroll
    for (int ky = 0; ky < 3; ky++)
        #pragma unroll
        for (int kx = 0; kx < 3; kx++) {
            int ti = ky * 3 + kx;
            if (VM & (1u << ti))
                pc += __popc(row[ky * C2_LW + c0 + kx] ^ wreg[ti]);
        }
    const int nv = ((VM>>0)&1)+((VM>>1)&1)+((VM>>2)&1)+((VM>>3)&1)+((VM>>4)&1)
                 + ((VM>>5)&1)+((VM>>6)&1)+((VM>>7)&1)+((VM>>8)&1);
    return pc <= ((32 * nv - T) >> 1);
}

template<unsigned VM>
static __device__ __forceinline__ bool px3(const uint64_t* row, int c0,
                                           const uint64_t* wreg, int T) {
    int pc = 0;
    #pragma unroll
    for (int ky = 0; ky < 3; ky++)
        #pragma unroll
        for (int kx = 0; kx < 3; kx++) {
            int ti = ky * 3 + kx;
            if (VM & (1u << ti))
                pc += __popcll(row[ky * C3_LW + c0 + kx] ^ wreg[ti]);
        }
    const int nv = ((VM>>0)&1)+((VM>>1)&1)+((VM>>2)&1)+((VM>>3)&1)+((VM>>4)&1)
                 + ((VM>>5)&1)+((VM>>6)&1)+((VM>>7)&1)+((VM>>8)&1);
    return pc <= ((64 * nv - T) >> 1);
}

template<unsigned VM>
static __device__ __forceinline__ bool px4(const uint64_t* base, int c0,
                                           const ulonglong2* wreg, int T) {
    int pc = 0;
    #pragma unroll
    for (int ky = 0; ky < 3; ky++)
        #pragma unroll
        for (int kx = 0; kx < 3; kx++) {
            int ti = ky * 3 + kx;
            if (VM & (1u << ti)) {
                int a = (ky * C4_LW + c0 + kx) * 2;
                pc += __popcll(base[a] ^ wreg[ti].x);
                pc += __popcll(base[a + 1] ^ wreg[ti].y);
            }
        }
    const int nv = ((VM>>0)&1)+((VM>>1)&1)+((VM>>2)&1)+((VM>>3)&1)+((VM>>4)&1)
                 + ((VM>>5)&1)+((VM>>6)&1)+((VM>>7)&1)+((VM>>8)&1);
    return pc <= ((128 * nv - T) >> 1);
}

// conv2: A1 [32][224][224] u32 -> A2 [32][112][112] u64.
// grid 32*56: b, oyq(0..27), h(0..1). waves w=0..3 -> oy=oyq*4+w; 56 px each.
__global__ __launch_bounds__(256) void k_conv2(
    const uint32_t* __restrict__ A1, const uint32_t* __restrict__ W2g,
    const int* __restrict__ T2, uint64_t* __restrict__ A2)
{
    __shared__ uint32_t lds[9 * C2_LW];
    int bi = blockIdx.x;
    int b = bi / 56, rem = bi % 56;
    int oyq = rem >> 1, h = rem & 1;
    int xs = h * 56;
    int tid = threadIdx.x;
    const uint32_t* ap = A1 + (size_t)b * 50176;
    for (int i = tid; i < 9 * C2_LW; i += 256) {
        int r = i / C2_LW, c = i - r * C2_LW;
        int iy = oyq * 8 - 1 + r, ix = 2 * xs - 1 + c;
        uint32_t v = 0;
        if ((unsigned)iy < 224u && (unsigned)ix < 224u) v = ap[iy * 224 + ix];
        lds[i] = v;
    }
    __syncthreads();

    int w = tid >> 6, lane = tid & 63;
    int oy = oyq * 4 + w;
    uint32_t wreg[9];
    #pragma unroll
    for (int ti = 0; ti < 9; ti++) wreg[ti] = W2g[lane * 9 + ti];
    int T = T2[lane];
    const uint32_t* lrow = lds + 2 * w * C2_LW;
    uint64_t* dst = A2 + (size_t)b * 12544 + oy * 112 + xs;
    bool left = (xs == 0);

    if (oy == 0) {
        int lx0 = 0;
        if (left) {
            uint64_t wd = __ballot(px2<0x1B0>(lrow, 0, wreg, T));
            if (lane == 0) dst[0] = wd;
            lx0 = 1;
        }
        for (int lx = lx0; lx < 56; lx++) {
            uint64_t wd = __ballot(px2<0x1F8>(lrow, 2 * lx, wreg, T));
            if (lane == 0) dst[lx] = wd;
        }
    } else {
        int lx0 = 0;
        if (left) {
            uint64_t wd = __ballot(px2<0x1B6>(lrow, 0, wreg, T));
            if (lane == 0) dst[0] = wd;
            lx0 = 1;
        }
        for (int lx = lx0; lx < 56; lx++) {
            uint64_t wd = __ballot(px2<0x1FF>(lrow, 2 * lx, wreg, T));
            if (lane == 0) dst[lx] = wd;
        }
    }
}

// conv3: A2 -> A3 planar [2][32][56][56] u64.
// grid 32*56: b, oyp(0..27), h(0..1). waves: oy=oyp*2+(w>>1), g=w&1; 28 px each.
__global__ __launch_bounds__(256) void k_conv3(
    const uint64_t* __restrict__ A2, const uint64_t* __restrict__ W3g,
    const int* __restrict__ T3, uint64_t* __restrict__ A3)
{
    __shared__ uint64_t lds[5 * C3_LW];
    int bi = blockIdx.x;
    int b = bi / 56, rem = bi % 56;
    int oyp = rem >> 1, h = rem & 1;
    int xs = h * 28;
    int tid = threadIdx.x;
    const uint64_t* ap = A2 + (size_t)b * 12544;
    for (int i = tid; i < 5 * C3_LW; i += 256) {
        int r = i / C3_LW, c = i - r * C3_LW;
        int iy = oyp * 4 - 1 + r, ix = 2 * xs - 1 + c;
        uint64_t v = 0;
        if ((unsigned)iy < 112u && (unsigned)ix < 112u) v = ap[iy * 112 + ix];
        lds[i] = v;
    }
    __syncthreads();

    int w = tid >> 6, lane = tid & 63;
    int oy = oyp * 2 + (w >> 1);
    int g  = w & 1;
    int oc = g * 64 + lane;
    uint64_t wreg[9];
    #pragma unroll
    for (int ti = 0; ti < 9; ti++) wreg[ti] = W3g[oc * 9 + ti];
    int T = T3[oc];
    const uint64_t* lrow = lds + 2 * (w >> 1) * C3_LW;
    uint64_t* dst = A3 + (size_t)g * 100352 + (size_t)b * 3136 + oy * 56 + xs;
    bool left = (xs == 0);

    if (oy == 0) {
        int lx0 = 0;
        if (left) {
            uint64_t wd = __ballot(px3<0x1B0>(lrow, 0, wreg, T));
            if (lane == 0) dst[0] = wd;
            lx0 = 1;
        }
        for (int lx = lx0; lx < 28; lx++) {
            uint64_t wd = __ballot(px3<0x1F8>(lrow, 2 * lx, wreg, T));
            if (lane == 0) dst[lx] = wd;
        }
    } else {
        int lx0 = 0;
        if (left) {
            uint64_t wd = __ballot(px3<0x1B6>(lrow, 0, wreg, T));
            if (lane == 0) dst[0] = wd;
            lx0 = 1;
        }
        for (int lx = lx0; lx < 28; lx++) {
            uint64_t wd = __ballot(px3<0x1FF>(lrow, 2 * lx, wreg, T));
            if (lane == 0) dst[lx] = wd;
        }
    }
}

// conv4: A3 planar -> A4 planar [4][32][28][28] u64.
// grid 32*56: b, oy(0..27), h(0..1). waves g=w; 14 px each.
__global__ __launch_bounds__(256) void k_conv4(
    const uint64_t* __restrict__ A3, const uint64_t* __restrict__ W4g,
    const int* __restrict__ T4, uint64_t* __restrict__ A4)
{
    __shared__ uint64_t lds[3 * C4_LW * 2];   // [r][c][plane]
    int bi = blockIdx.x;
    int b = bi / 56, rem = bi % 56;
    int oy = rem >> 1, h = rem & 1;
    int xs = h * 14;
    int tid = threadIdx.x;
    const uint64_t* ap = A3 + (size_t)b * 3136;
    for (int i = tid; i < 3 * C4_LW * 2; i += 256) {
        int pl = i & 1, j = i >> 1;
        int r = j / C4_LW, c = j - r * C4_LW;
        int iy = 2 * oy - 1 + r, ix = 2 * xs - 1 + c;
        uint64_t v = 0;
        if ((unsigned)iy < 56u && (unsigned)ix < 56u)
            v = ap[(size_t)pl * 100352 + iy * 56 + ix];
        lds[(r * C4_LW + c) * 2 + pl] = v;
    }
    __syncthreads();

    int w = tid >> 6, lane = tid & 63;
    int oc = w * 64 + lane;
    ulonglong2 wreg[9];
    const ulonglong2* wp = (const ulonglong2*)(W4g + oc * 18);
    #pragma unroll
    for (int ti = 0; ti < 9; ti++) wreg[ti] = wp[ti];
    int T = T4[oc];
    uint64_t* dst = A4 + (size_t)w * 25088 + (size_t)b * 784 + oy * 28 + xs;
    bool left = (xs == 0);

    if (oy == 0) {
        int lx0 = 0;
        if (left) {
            uint64_t wd = __ballot(px4<0x1B0>(lds, 0, wreg, T));
            if (lane == 0) dst[0] = wd;
            lx0 = 1;
        }
        for (int lx = lx0; lx < 14; lx++) {
            uint64_t wd = __ballot(px4<0x1F8>(lds, 2 * lx, wreg, T));
            if (lane == 0) dst[lx] = wd;
        }
    } else {
        int lx0 = 0;
        if (left) {
            uint64_t wd = __ballot(px4<0x1B6>(lds, 0, wreg, T));
            if (lane == 0) dst[0] = wd;
            lx0 = 1;
        }
        for (int lx = lx0; lx < 14; lx++) {
            uint64_t wd = __ballot(px4<0x1FF>(lds, 2 * lx, wreg, T));
            if (lane == 0) dst[lx] = wd;
        }
    }
}

// ---------------- mean over HxW + fc (A4 planar u64) ----------------
__global__ __launch_bounds__(1024) void k_tail(
    const uint64_t* __restrict__ A4, const float* __restrict__ fcw,
    const float* __restrict__ fcb, float* __restrict__ out)
{
    int b = blockIdx.x;
    int tid = threadIdx.x;
    int c = tid & 255, chunk = tid >> 8;
    int g = c >> 6, bit = c & 63;
    const uint64_t* base = A4 + (size_t)g * 25088 + (size_t)b * 784;
    int cnt = 0;
    for (int p = chunk * 196; p < (chunk + 1) * 196; p++)
        cnt += (int)((base[p] >> bit) & 1ull);

    __shared__ int cnts[4][256];
    __shared__ double r0[256], r1[256];
    cnts[chunk][c] = cnt;
    __syncthreads();
    if (tid < 256) {
        int tot = cnts[0][c] + cnts[1][c] + cnts[2][c] + cnts[3][c];
        double mean = (2.0 * (double)tot - 784.0) * (1.0 / 784.0);
        r0[c] = (double)fcw[c]       * mean;
        r1[c] = (double)fcw[256 + c] * mean;
    }
    __syncthreads();
    for (int s = 128; s > 0; s >>= 1) {
        if (tid < s) { r0[tid] += r0[tid + s]; r1[tid] += r1[tid + s]; }
        __syncthreads();
    }
    if (tid == 0) {
        out[b * 2 + 0] = (float)(r0[0] + (double)fcb[0]);
        out[b * 2 + 1] = (float)(r1[0] + (double)fcb[1]);
    }
}

extern "C" void kernel_launch(void* const* d_in, const int* in_sizes, int n_in,
                              void* d_out, int out_size, void* d_ws, size_t ws_size,
                              hipStream_t stream) {
    const float* x   = (const float*)d_in[0];
    const float* w1  = (const float*)d_in[1];
    const float* w2  = (const float*)d_in[2];
    const float* w3  = (const float*)d_in[3];
    const float* w4  = (const float*)d_in[4];
    const float* g1 = (const float*)d_in[5],  *b1 = (const float*)d_in[6],
               * m1 = (const float*)d_in[7],  *v1 = (const float*)d_in[8];
    const float* g2 = (const float*)d_in[9],  *b2 = (const float*)d_in[10],
               * m2 = (const float*)d_in[11], *v2 = (const float*)d_in[12];
    const float* g3 = (const float*)d_in[13], *b3 = (const float*)d_in[14],
               * m3 = (const float*)d_in[15], *v3 = (const float*)d_in[16];
    const float* g4 = (const float*)d_in[17], *b4 = (const float*)d_in[18],
               * m4 = (const float*)d_in[19], *v4 = (const float*)d_in[20];
    const float* fcw = (const float*)d_in[21];
    const float* fcb = (const float*)d_in[22];
    float* out = (float*)d_out;

    char* ws = (char*)d_ws;
    float2*   S1  = (float2*)(ws + OFF_S1);
    float*    W1T = (float*)(ws + OFF_W1T);
    int*      T2  = (int*)(ws + OFF_T2);
    int*      P2  = (int*)(ws + OFF_P2);
    int*      T3  = (int*)(ws + OFF_T3);
    int*      P3  = (int*)(ws + OFF_P3);
    int*      T4  = (int*)(ws + OFF_T4);
    int*      P4  = (int*)(ws + OFF_P4);
    uint32_t* W2  = (uint32_t*)(ws + OFF_W2);
    uint64_t* W3  = (uint64_t*)(ws + OFF_W3);
    uint64_t* W4  = (uint64_t*)(ws + OFF_W4);
    uint32_t* A1  = (uint32_t*)(ws + OFF_A1);
    uint64_t* A2  = (uint64_t*)(ws + OFF_A2);
    uint64_t* A3  = (uint64_t*)(ws + OFF_A3);
    uint64_t* A4  = (uint64_t*)(ws + OFF_A4);

    hipLaunchKernelGGL(k_prep, dim3(1590), dim3(256), 0, stream,
                       w1, w2, w3, w4,
                       g1, b1, m1, v1, g2, b2, m2, v2,
                       g3, b3, m3, v3, g4, b4, m4, v4,
                       S1, W1T, T2, P2, T3, P3, T4, P4, W2, W3, W4);
    hipLaunchKernelGGL(k_conv1, dim3(3136), dim3(256), 0, stream, x, w1, S1, A1);
    hipLaunchKernelGGL(k_conv2, dim3(1792), dim3(256), 0, stream, A1, W2, T2, A2);
    hipLaunchKernelGGL(k_conv3, dim3(1792), dim3(256), 0, stream, A2, W3, T3, A3);
    hipLaunchKernelGGL(k_conv4, dim3(1792), dim3(256), 0, stream, A3, W4, T4, A4);
    hipLaunchKernelGGL(k_tail,  dim3(32),   dim3(1024), 0, stream, A4, fcw, fcb, out);
}